// Round 1
// baseline (1806.176 us; speedup 1.0000x reference)
//
#include <hip/hip_runtime.h>
#include <hip/hip_bf16.h>

// GCN (3-layer, JK=sum) on MI355X.
// Pipeline per call:
//   memset cnt; out = x (memcpyAsync)
//   k_count  : in-degree histogram (int atomics)
//   k_scan   : exclusive prefix sum -> rowptr, cursor   (1 block, 1024 thr)
//   k_dinv   : dinv = rsqrt(deg+1)
//   k_fill   : CSR column fill (cursor atomics)
//   per layer l:
//     k_gemm : hs = (h @ W[l]) * dinv[row]        (W in LDS, 8x4 reg tile)
//     k_spmm : agg = dinv[d]*(sum_src hs + hs[d]) + b; relu; (+BN partial stats)
//     l<2: k_bnstats (reduce partials -> scale/shift), k_bn (normalize in place, out+=h)
//     l==2: k_spmm mode 1 adds relu(...) directly into out.

constexpr int NN = 100000;
constexpr int EE = 1600000;
constexpr int DD = 128;
constexpr float BN_EPS = 1e-5f;
constexpr int NPAD = 100096;         // node-count padded to mult of 128
constexpr int SPMM_BLOCKS = 1024;

__global__ void k_count(const int* __restrict__ dst, int* __restrict__ cnt) {
  int e = blockIdx.x * 256 + threadIdx.x;
  if (e < EE) atomicAdd(&cnt[dst[e]], 1);
}

__global__ __launch_bounds__(1024)
void k_scan(const int* __restrict__ cnt, int* __restrict__ rowptr,
            int* __restrict__ cursor) {
  __shared__ int part[1024];
  const int t = threadIdx.x;
  const int CH = (NN + 1023) / 1024;   // 98
  const int i0 = t * CH;
  const int i1 = min(i0 + CH, NN);
  int sum = 0;
  for (int i = i0; i < i1; ++i) sum += cnt[i];
  part[t] = sum;
  __syncthreads();
  // Hillis-Steele inclusive scan over 1024 partials
  for (int off = 1; off < 1024; off <<= 1) {
    int x = 0;
    if (t >= off) x = part[t - off];
    __syncthreads();
    part[t] += x;
    __syncthreads();
  }
  int run = part[t] - sum;             // exclusive base
  for (int i = i0; i < i1; ++i) {
    rowptr[i] = run;
    cursor[i] = run;
    run += cnt[i];
  }
  if (t == 1023) rowptr[NN] = part[1023];
}

__global__ void k_dinv(const int* __restrict__ cnt, float* __restrict__ dinv) {
  int i = blockIdx.x * 256 + threadIdx.x;
  if (i < NN) dinv[i] = rsqrtf((float)cnt[i] + 1.0f);
}

__global__ void k_fill(const int* __restrict__ src, const int* __restrict__ dst,
                       int* __restrict__ cursor, int* __restrict__ col) {
  int e = blockIdx.x * 256 + threadIdx.x;
  if (e < EE) {
    int d = dst[e];
    int pos = atomicAdd(&cursor[d], 1);
    col[pos] = src[e];
  }
}

// hs[r][c] = dinv[r] * sum_k h[r][k] * W[k][c]
__global__ __launch_bounds__(256, 2)
void k_gemm(const float* __restrict__ h, const float* __restrict__ Wl,
            const float* __restrict__ dinv, float* __restrict__ hs) {
  __shared__ float Wlds[DD * DD];      // 64 KB
  for (int i = threadIdx.x; i < DD * DD; i += 256) Wlds[i] = Wl[i];
  __syncthreads();
  const int lane = threadIdx.x & 31;
  const int g = threadIdx.x >> 5;      // 0..7
  const int c4 = lane * 4;
  const int rbase = blockIdx.x * 64 + g * 8;
  if (rbase >= NN) return;
  float4 acc[8];
#pragma unroll
  for (int i = 0; i < 8; ++i) acc[i] = make_float4(0.f, 0.f, 0.f, 0.f);
  const bool full = (rbase + 8 <= NN);
  for (int k = 0; k < DD; k += 4) {
    float4 hv[8];
    if (full) {
#pragma unroll
      for (int i = 0; i < 8; ++i)
        hv[i] = *(const float4*)&h[(size_t)(rbase + i) * DD + k];
    } else {
#pragma unroll
      for (int i = 0; i < 8; ++i)
        hv[i] = (rbase + i < NN)
                    ? *(const float4*)&h[(size_t)(rbase + i) * DD + k]
                    : make_float4(0.f, 0.f, 0.f, 0.f);
    }
    const float4 w0 = *(const float4*)&Wlds[(k + 0) * DD + c4];
    const float4 w1 = *(const float4*)&Wlds[(k + 1) * DD + c4];
    const float4 w2 = *(const float4*)&Wlds[(k + 2) * DD + c4];
    const float4 w3 = *(const float4*)&Wlds[(k + 3) * DD + c4];
#pragma unroll
    for (int i = 0; i < 8; ++i) {
      acc[i].x = fmaf(hv[i].x, w0.x, acc[i].x);
      acc[i].x = fmaf(hv[i].y, w1.x, acc[i].x);
      acc[i].x = fmaf(hv[i].z, w2.x, acc[i].x);
      acc[i].x = fmaf(hv[i].w, w3.x, acc[i].x);
      acc[i].y = fmaf(hv[i].x, w0.y, acc[i].y);
      acc[i].y = fmaf(hv[i].y, w1.y, acc[i].y);
      acc[i].y = fmaf(hv[i].z, w2.y, acc[i].y);
      acc[i].y = fmaf(hv[i].w, w3.y, acc[i].y);
      acc[i].z = fmaf(hv[i].x, w0.z, acc[i].z);
      acc[i].z = fmaf(hv[i].y, w1.z, acc[i].z);
      acc[i].z = fmaf(hv[i].z, w2.z, acc[i].z);
      acc[i].z = fmaf(hv[i].w, w3.z, acc[i].z);
      acc[i].w = fmaf(hv[i].x, w0.w, acc[i].w);
      acc[i].w = fmaf(hv[i].y, w1.w, acc[i].w);
      acc[i].w = fmaf(hv[i].z, w2.w, acc[i].w);
      acc[i].w = fmaf(hv[i].w, w3.w, acc[i].w);
    }
  }
#pragma unroll
  for (int i = 0; i < 8; ++i) {
    int r = rbase + i;
    if (r < NN) {
      float dv = dinv[r];
      float4 o = acc[i];
      o.x *= dv; o.y *= dv; o.z *= dv; o.w *= dv;
      *(float4*)&hs[(size_t)r * DD + c4] = o;
    }
  }
}

// mode 0: hout = relu(dinv*(sum+self)+b), write BN partial stats
// mode 1: out += relu(...)
__global__ __launch_bounds__(256)
void k_spmm(const float* __restrict__ hs, const int* __restrict__ rowptr,
            const int* __restrict__ col, const float* __restrict__ dinv,
            const float* __restrict__ bias, float* __restrict__ hout,
            float* __restrict__ out, float* __restrict__ partials,
            const int mode) {
  const int lane = threadIdx.x & 31;
  const int g = threadIdx.x >> 5;
  const int c4 = lane * 4;
  const float4 bv = *(const float4*)&bias[c4];
  float4 bsum = make_float4(0.f, 0.f, 0.f, 0.f);
  float4 bsq = make_float4(0.f, 0.f, 0.f, 0.f);
  for (int d0 = blockIdx.x * 8; d0 < NN; d0 += gridDim.x * 8) {
    const int d = d0 + g;
    if (d < NN) {
      const int rp1 = rowptr[d + 1];
      float4 acc = *(const float4*)&hs[(size_t)d * DD + c4];  // self-loop term
      for (int j = rowptr[d]; j < rp1; ++j) {
        const int s = col[j];
        const float4 v = *(const float4*)&hs[(size_t)s * DD + c4];
        acc.x += v.x; acc.y += v.y; acc.z += v.z; acc.w += v.w;
      }
      const float dv = dinv[d];
      float4 o;
      o.x = fmaxf(fmaf(acc.x, dv, bv.x), 0.f);
      o.y = fmaxf(fmaf(acc.y, dv, bv.y), 0.f);
      o.z = fmaxf(fmaf(acc.z, dv, bv.z), 0.f);
      o.w = fmaxf(fmaf(acc.w, dv, bv.w), 0.f);
      if (mode == 0) {
        *(float4*)&hout[(size_t)d * DD + c4] = o;
        bsum.x += o.x; bsum.y += o.y; bsum.z += o.z; bsum.w += o.w;
        bsq.x += o.x * o.x; bsq.y += o.y * o.y;
        bsq.z += o.z * o.z; bsq.w += o.w * o.w;
      } else {
        float4 po = *(const float4*)&out[(size_t)d * DD + c4];
        po.x += o.x; po.y += o.y; po.z += o.z; po.w += o.w;
        *(float4*)&out[(size_t)d * DD + c4] = po;
      }
    }
  }
  if (mode == 0) {
    __shared__ float red[256 * 8];
    float* my = &red[threadIdx.x * 8];
    my[0] = bsum.x; my[1] = bsum.y; my[2] = bsum.z; my[3] = bsum.w;
    my[4] = bsq.x;  my[5] = bsq.y;  my[6] = bsq.z;  my[7] = bsq.w;
    __syncthreads();
    const int t = threadIdx.x;          // output slot t = lane*8 + q
    float s = 0.f;
#pragma unroll
    for (int gg = 0; gg < 8; ++gg) s += red[gg * 256 + t];
    partials[(size_t)blockIdx.x * 256 + t] = s;
  }
}

// reduce per-block partials -> per-channel scale/shift
__global__ __launch_bounds__(256)
void k_bnstats(const float* __restrict__ partials, float* __restrict__ ss,
               const float* __restrict__ gamma, const float* __restrict__ beta,
               const int nblocks) {
  __shared__ float tot[256];            // [kind*128 + c]
  const int t = threadIdx.x;
  float s = 0.f;
  for (int bk = 0; bk < nblocks; ++bk) s += partials[(size_t)bk * 256 + t];
  const int l = t >> 3, q = t & 7;
  const int c = l * 4 + (q & 3), kind = q >> 2;
  tot[kind * 128 + c] = s;
  __syncthreads();
  if (t < 128) {
    const float m = tot[t] * (1.0f / NN);
    const float var = tot[128 + t] * (1.0f / NN) - m * m;
    const float rs = rsqrtf(var + BN_EPS);
    const float sc = rs * gamma[t];
    ss[t] = sc;
    ss[128 + t] = beta[t] - m * sc;
  }
}

// h = h*scale + shift (in place); out += h
__global__ __launch_bounds__(256)
void k_bn(float* __restrict__ h, float* __restrict__ out,
          const float* __restrict__ ss) {
  const int i4 = blockIdx.x * 256 + threadIdx.x;   // exactly N*D/4 threads
  const int c4 = (i4 & 31) * 4;
  const float4 sc = *(const float4*)&ss[c4];
  const float4 sh = *(const float4*)&ss[128 + c4];
  float4 hv = ((const float4*)h)[i4];
  float4 o;
  o.x = fmaf(hv.x, sc.x, sh.x);
  o.y = fmaf(hv.y, sc.y, sh.y);
  o.z = fmaf(hv.z, sc.z, sh.z);
  o.w = fmaf(hv.w, sc.w, sh.w);
  ((float4*)h)[i4] = o;
  float4 po = ((float4*)out)[i4];
  po.x += o.x; po.y += o.y; po.z += o.z; po.w += o.w;
  ((float4*)out)[i4] = po;
}

extern "C" void kernel_launch(void* const* d_in, const int* in_sizes, int n_in,
                              void* d_out, int out_size, void* d_ws, size_t ws_size,
                              hipStream_t stream) {
  const float* x = (const float*)d_in[0];
  const int* ei = (const int*)d_in[1];
  const float* W = (const float*)d_in[2];
  const float* b = (const float*)d_in[3];
  const float* gamma = (const float*)d_in[4];
  const float* beta = (const float*)d_in[5];
  float* out = (float*)d_out;
  const int* srcv = ei;
  const int* dstv = ei + EE;

  char* w = (char*)d_ws;
  int* cnt = (int*)w;        w += (size_t)NPAD * 4;
  int* rowptr = (int*)w;     w += (size_t)NPAD * 4;
  int* cursor = (int*)w;     w += (size_t)NPAD * 4;
  int* col = (int*)w;        w += (size_t)EE * 4;
  float* dinv = (float*)w;   w += (size_t)NPAD * 4;
  float* ss = (float*)w;     w += 256 * 4;
  float* partials = (float*)w; w += (size_t)SPMM_BLOCKS * 256 * 4;
  float* bufA = (float*)w;   w += (size_t)NN * DD * 4;
  float* bufB = (float*)w;   /* end */

  hipMemsetAsync(cnt, 0, NN * sizeof(int), stream);
  hipMemcpyAsync(out, x, (size_t)NN * DD * sizeof(float),
                 hipMemcpyDeviceToDevice, stream);

  k_count<<<(EE + 255) / 256, 256, 0, stream>>>(dstv, cnt);
  k_scan<<<1, 1024, 0, stream>>>(cnt, rowptr, cursor);
  k_dinv<<<(NN + 255) / 256, 256, 0, stream>>>(cnt, dinv);
  k_fill<<<(EE + 255) / 256, 256, 0, stream>>>(srcv, dstv, cursor, col);

  const float* hcur = x;
  for (int l = 0; l < 3; ++l) {
    k_gemm<<<(NN + 63) / 64, 256, 0, stream>>>(hcur, W + (size_t)l * DD * DD,
                                               dinv, bufB);
    if (l < 2) {
      k_spmm<<<SPMM_BLOCKS, 256, 0, stream>>>(bufB, rowptr, col, dinv,
                                              b + l * DD, bufA, nullptr,
                                              partials, 0);
      k_bnstats<<<1, 256, 0, stream>>>(partials, ss, gamma + l * DD,
                                       beta + l * DD, SPMM_BLOCKS);
      k_bn<<<(NN * DD / 4) / 256, 256, 0, stream>>>(bufA, out, ss);
      hcur = bufA;
    } else {
      k_spmm<<<SPMM_BLOCKS, 256, 0, stream>>>(bufB, rowptr, col, dinv,
                                              b + l * DD, nullptr, out,
                                              nullptr, 1);
    }
  }
}

// Round 2
// 1346.487 us; speedup vs baseline: 1.3414x; 1.3414x over previous
//
#include <hip/hip_runtime.h>
#include <hip/hip_bf16.h>

// GCN (3-layer, JK=sum) on MI355X.
// R2: BN stats via per-block LDS reduce + 256 fp32 atomicAdds into a global
//     512-float accumulator (was: 1MB partials buffer + single-block serial
//     reduce = 238us/layer, latency-bound at 0.047% occupancy).

constexpr int NN = 100000;
constexpr int EE = 1600000;
constexpr int DD = 128;
constexpr float BN_EPS = 1e-5f;
constexpr int NPAD = 100096;
constexpr int SPMM_BLOCKS = 1024;

__global__ void k_count(const int* __restrict__ dst, int* __restrict__ cnt) {
  int e = blockIdx.x * 256 + threadIdx.x;
  if (e < EE) atomicAdd(&cnt[dst[e]], 1);
}

__global__ __launch_bounds__(1024)
void k_scan(const int* __restrict__ cnt, int* __restrict__ rowptr,
            int* __restrict__ cursor) {
  __shared__ int part[1024];
  const int t = threadIdx.x;
  const int CH = (NN + 1023) / 1024;   // 98
  const int i0 = t * CH;
  const int i1 = min(i0 + CH, NN);
  int sum = 0;
  for (int i = i0; i < i1; ++i) sum += cnt[i];
  part[t] = sum;
  __syncthreads();
  for (int off = 1; off < 1024; off <<= 1) {
    int x = 0;
    if (t >= off) x = part[t - off];
    __syncthreads();
    part[t] += x;
    __syncthreads();
  }
  int run = part[t] - sum;             // exclusive base
  for (int i = i0; i < i1; ++i) {
    rowptr[i] = run;
    cursor[i] = run;
    run += cnt[i];
  }
  if (t == 1023) rowptr[NN] = part[1023];
}

__global__ void k_dinv(const int* __restrict__ cnt, float* __restrict__ dinv) {
  int i = blockIdx.x * 256 + threadIdx.x;
  if (i < NN) dinv[i] = rsqrtf((float)cnt[i] + 1.0f);
}

__global__ void k_fill(const int* __restrict__ src, const int* __restrict__ dst,
                       int* __restrict__ cursor, int* __restrict__ col) {
  int e = blockIdx.x * 256 + threadIdx.x;
  if (e < EE) {
    int d = dst[e];
    int pos = atomicAdd(&cursor[d], 1);
    col[pos] = src[e];
  }
}

// hs[r][c] = dinv[r] * sum_k h[r][k] * W[k][c]
__global__ __launch_bounds__(256, 2)
void k_gemm(const float* __restrict__ h, const float* __restrict__ Wl,
            const float* __restrict__ dinv, float* __restrict__ hs) {
  __shared__ float Wlds[DD * DD];      // 64 KB
  for (int i = threadIdx.x; i < DD * DD; i += 256) Wlds[i] = Wl[i];
  __syncthreads();
  const int lane = threadIdx.x & 31;
  const int g = threadIdx.x >> 5;      // 0..7
  const int c4 = lane * 4;
  const int rbase = blockIdx.x * 64 + g * 8;
  if (rbase >= NN) return;
  float4 acc[8];
#pragma unroll
  for (int i = 0; i < 8; ++i) acc[i] = make_float4(0.f, 0.f, 0.f, 0.f);
  const bool full = (rbase + 8 <= NN);
  for (int k = 0; k < DD; k += 4) {
    float4 hv[8];
    if (full) {
#pragma unroll
      for (int i = 0; i < 8; ++i)
        hv[i] = *(const float4*)&h[(size_t)(rbase + i) * DD + k];
    } else {
#pragma unroll
      for (int i = 0; i < 8; ++i)
        hv[i] = (rbase + i < NN)
                    ? *(const float4*)&h[(size_t)(rbase + i) * DD + k]
                    : make_float4(0.f, 0.f, 0.f, 0.f);
    }
    const float4 w0 = *(const float4*)&Wlds[(k + 0) * DD + c4];
    const float4 w1 = *(const float4*)&Wlds[(k + 1) * DD + c4];
    const float4 w2 = *(const float4*)&Wlds[(k + 2) * DD + c4];
    const float4 w3 = *(const float4*)&Wlds[(k + 3) * DD + c4];
#pragma unroll
    for (int i = 0; i < 8; ++i) {
      acc[i].x = fmaf(hv[i].x, w0.x, acc[i].x);
      acc[i].x = fmaf(hv[i].y, w1.x, acc[i].x);
      acc[i].x = fmaf(hv[i].z, w2.x, acc[i].x);
      acc[i].x = fmaf(hv[i].w, w3.x, acc[i].x);
      acc[i].y = fmaf(hv[i].x, w0.y, acc[i].y);
      acc[i].y = fmaf(hv[i].y, w1.y, acc[i].y);
      acc[i].y = fmaf(hv[i].z, w2.y, acc[i].y);
      acc[i].y = fmaf(hv[i].w, w3.y, acc[i].y);
      acc[i].z = fmaf(hv[i].x, w0.z, acc[i].z);
      acc[i].z = fmaf(hv[i].y, w1.z, acc[i].z);
      acc[i].z = fmaf(hv[i].z, w2.z, acc[i].z);
      acc[i].z = fmaf(hv[i].w, w3.z, acc[i].z);
      acc[i].w = fmaf(hv[i].x, w0.w, acc[i].w);
      acc[i].w = fmaf(hv[i].y, w1.w, acc[i].w);
      acc[i].w = fmaf(hv[i].z, w2.w, acc[i].w);
      acc[i].w = fmaf(hv[i].w, w3.w, acc[i].w);
    }
  }
#pragma unroll
  for (int i = 0; i < 8; ++i) {
    int r = rbase + i;
    if (r < NN) {
      float dv = dinv[r];
      float4 o = acc[i];
      o.x *= dv; o.y *= dv; o.z *= dv; o.w *= dv;
      *(float4*)&hs[(size_t)r * DD + c4] = o;
    }
  }
}

// mode 0: hout = relu(dinv*(sum+self)+b); atomic-accumulate BN stats into stat[256]
// mode 1: out += relu(...)
__global__ __launch_bounds__(256)
void k_spmm(const float* __restrict__ hs, const int* __restrict__ rowptr,
            const int* __restrict__ col, const float* __restrict__ dinv,
            const float* __restrict__ bias, float* __restrict__ hout,
            float* __restrict__ out, float* __restrict__ stat,
            const int mode) {
  const int lane = threadIdx.x & 31;
  const int g = threadIdx.x >> 5;
  const int c4 = lane * 4;
  const float4 bv = *(const float4*)&bias[c4];
  float4 bsum = make_float4(0.f, 0.f, 0.f, 0.f);
  float4 bsq = make_float4(0.f, 0.f, 0.f, 0.f);
  for (int d0 = blockIdx.x * 8; d0 < NN; d0 += gridDim.x * 8) {
    const int d = d0 + g;
    if (d < NN) {
      const int rp1 = rowptr[d + 1];
      float4 acc = *(const float4*)&hs[(size_t)d * DD + c4];  // self-loop term
      for (int j = rowptr[d]; j < rp1; ++j) {
        const int s = col[j];
        const float4 v = *(const float4*)&hs[(size_t)s * DD + c4];
        acc.x += v.x; acc.y += v.y; acc.z += v.z; acc.w += v.w;
      }
      const float dv = dinv[d];
      float4 o;
      o.x = fmaxf(fmaf(acc.x, dv, bv.x), 0.f);
      o.y = fmaxf(fmaf(acc.y, dv, bv.y), 0.f);
      o.z = fmaxf(fmaf(acc.z, dv, bv.z), 0.f);
      o.w = fmaxf(fmaf(acc.w, dv, bv.w), 0.f);
      if (mode == 0) {
        *(float4*)&hout[(size_t)d * DD + c4] = o;
        bsum.x += o.x; bsum.y += o.y; bsum.z += o.z; bsum.w += o.w;
        bsq.x += o.x * o.x; bsq.y += o.y * o.y;
        bsq.z += o.z * o.z; bsq.w += o.w * o.w;
      } else {
        float4 po = *(const float4*)&out[(size_t)d * DD + c4];
        po.x += o.x; po.y += o.y; po.z += o.z; po.w += o.w;
        *(float4*)&out[(size_t)d * DD + c4] = po;
      }
    }
  }
  if (mode == 0) {
    __shared__ float red[256 * 8];
    float* my = &red[threadIdx.x * 8];
    my[0] = bsum.x; my[1] = bsum.y; my[2] = bsum.z; my[3] = bsum.w;
    my[4] = bsq.x;  my[5] = bsq.y;  my[6] = bsq.z;  my[7] = bsq.w;
    __syncthreads();
    const int t = threadIdx.x;          // slot t = lane*8 + q
    float s = 0.f;
#pragma unroll
    for (int gg = 0; gg < 8; ++gg) s += red[gg * 256 + t];
    atomicAdd(&stat[t], s);
  }
}

// finalize: stat[256] -> per-channel scale/shift
__global__ __launch_bounds__(256)
void k_bnfin(const float* __restrict__ stat, float* __restrict__ ss,
             const float* __restrict__ gamma, const float* __restrict__ beta) {
  __shared__ float tot[256];            // [kind*128 + c]
  const int t = threadIdx.x;
  const float s = stat[t];
  const int l = t >> 3, q = t & 7;
  const int c = l * 4 + (q & 3), kind = q >> 2;
  tot[kind * 128 + c] = s;
  __syncthreads();
  if (t < 128) {
    const float m = tot[t] * (1.0f / NN);
    const float var = tot[128 + t] * (1.0f / NN) - m * m;
    const float rs = rsqrtf(var + BN_EPS);
    const float sc = rs * gamma[t];
    ss[t] = sc;
    ss[128 + t] = beta[t] - m * sc;
  }
}

// h = h*scale + shift (in place); out += h
__global__ __launch_bounds__(256)
void k_bn(float* __restrict__ h, float* __restrict__ out,
          const float* __restrict__ ss) {
  const int i4 = blockIdx.x * 256 + threadIdx.x;   // exactly N*D/4 threads
  const int c4 = (i4 & 31) * 4;
  const float4 sc = *(const float4*)&ss[c4];
  const float4 sh = *(const float4*)&ss[128 + c4];
  float4 hv = ((const float4*)h)[i4];
  float4 o;
  o.x = fmaf(hv.x, sc.x, sh.x);
  o.y = fmaf(hv.y, sc.y, sh.y);
  o.z = fmaf(hv.z, sc.z, sh.z);
  o.w = fmaf(hv.w, sc.w, sh.w);
  ((float4*)h)[i4] = o;
  float4 po = ((float4*)out)[i4];
  po.x += o.x; po.y += o.y; po.z += o.z; po.w += o.w;
  ((float4*)out)[i4] = po;
}

extern "C" void kernel_launch(void* const* d_in, const int* in_sizes, int n_in,
                              void* d_out, int out_size, void* d_ws, size_t ws_size,
                              hipStream_t stream) {
  const float* x = (const float*)d_in[0];
  const int* ei = (const int*)d_in[1];
  const float* W = (const float*)d_in[2];
  const float* b = (const float*)d_in[3];
  const float* gamma = (const float*)d_in[4];
  const float* beta = (const float*)d_in[5];
  float* out = (float*)d_out;
  const int* srcv = ei;
  const int* dstv = ei + EE;

  char* w = (char*)d_ws;
  int* cnt = (int*)w;        w += (size_t)NPAD * 4;
  int* rowptr = (int*)w;     w += (size_t)NPAD * 4;
  int* cursor = (int*)w;     w += (size_t)NPAD * 4;
  int* col = (int*)w;        w += (size_t)EE * 4;
  float* dinv = (float*)w;   w += (size_t)NPAD * 4;
  float* ss = (float*)w;     w += 256 * 4;
  float* stat = (float*)w;   w += 512 * 4;        // 2 layers x 256 slots
  float* bufA = (float*)w;   w += (size_t)NN * DD * 4;
  float* bufB = (float*)w;   /* end */

  hipMemsetAsync(cnt, 0, NN * sizeof(int), stream);
  hipMemsetAsync(stat, 0, 512 * sizeof(float), stream);
  hipMemcpyAsync(out, x, (size_t)NN * DD * sizeof(float),
                 hipMemcpyDeviceToDevice, stream);

  k_count<<<(EE + 255) / 256, 256, 0, stream>>>(dstv, cnt);
  k_scan<<<1, 1024, 0, stream>>>(cnt, rowptr, cursor);
  k_dinv<<<(NN + 255) / 256, 256, 0, stream>>>(cnt, dinv);
  k_fill<<<(EE + 255) / 256, 256, 0, stream>>>(srcv, dstv, cursor, col);

  const float* hcur = x;
  for (int l = 0; l < 3; ++l) {
    k_gemm<<<(NN + 63) / 64, 256, 0, stream>>>(hcur, W + (size_t)l * DD * DD,
                                               dinv, bufB);
    if (l < 2) {
      k_spmm<<<SPMM_BLOCKS, 256, 0, stream>>>(bufB, rowptr, col, dinv,
                                              b + l * DD, bufA, nullptr,
                                              stat + l * 256, 0);
      k_bnfin<<<1, 256, 0, stream>>>(stat + l * 256, ss, gamma + l * DD,
                                     beta + l * DD);
      k_bn<<<(NN * DD / 4) / 256, 256, 0, stream>>>(bufA, out, ss);
      hcur = bufA;
    } else {
      k_spmm<<<SPMM_BLOCKS, 256, 0, stream>>>(bufB, rowptr, col, dinv,
                                              b + l * DD, nullptr, out,
                                              nullptr, 1);
    }
  }
}

// Round 3
// 1128.887 us; speedup vs baseline: 1.6000x; 1.1928x over previous
//
#include <hip/hip_runtime.h>
#include <hip/hip_bf16.h>

// GCN (3-layer, JK=sum) on MI355X.
// R3: hierarchical 3-phase scan (was: 1-block serial scan = 230us,
//     latency-bound at 0.149% occupancy).

constexpr int NN = 100000;
constexpr int EE = 1600000;
constexpr int DD = 128;
constexpr float BN_EPS = 1e-5f;
constexpr int NPAD = 100096;
constexpr int SPMM_BLOCKS = 1024;
constexpr int SCAN_BLOCKS = (NN + 255) / 256;   // 391

__global__ void k_count(const int* __restrict__ dst, int* __restrict__ cnt) {
  int e = blockIdx.x * 256 + threadIdx.x;
  if (e < EE) atomicAdd(&cnt[dst[e]], 1);
}

// Phase A: per-block exclusive scan of cnt -> lpre, block totals -> bsum
__global__ __launch_bounds__(256)
void k_scanA(const int* __restrict__ cnt, int* __restrict__ lpre,
             int* __restrict__ bsum) {
  __shared__ int s[256];
  const int t = threadIdx.x;
  const int i = blockIdx.x * 256 + t;
  const int v = (i < NN) ? cnt[i] : 0;
  s[t] = v;
  __syncthreads();
  for (int off = 1; off < 256; off <<= 1) {
    int x = (t >= off) ? s[t - off] : 0;
    __syncthreads();
    s[t] += x;
    __syncthreads();
  }
  if (i < NN) lpre[i] = s[t] - v;             // exclusive
  if (t == 255) bsum[blockIdx.x] = s[255];
}

// Phase B: scan the 391 block totals -> exclusive bbase
__global__ __launch_bounds__(512)
void k_scanB(const int* __restrict__ bsum, int* __restrict__ bbase) {
  __shared__ int s[512];
  const int t = threadIdx.x;
  const int v = (t < SCAN_BLOCKS) ? bsum[t] : 0;
  s[t] = v;
  __syncthreads();
  for (int off = 1; off < 512; off <<= 1) {
    int x = (t >= off) ? s[t - off] : 0;
    __syncthreads();
    s[t] += x;
    __syncthreads();
  }
  if (t < SCAN_BLOCKS) bbase[t] = s[t] - v;   // exclusive
}

// Phase C: rowptr/cursor = bbase[blk] + lpre; rowptr[NN] = EE (known total)
__global__ __launch_bounds__(256)
void k_scanC(const int* __restrict__ lpre, const int* __restrict__ bbase,
             int* __restrict__ rowptr, int* __restrict__ cursor) {
  const int i = blockIdx.x * 256 + threadIdx.x;
  if (i < NN) {
    const int r = bbase[blockIdx.x] + lpre[i];
    rowptr[i] = r;
    cursor[i] = r;
  }
  if (i == 0) rowptr[NN] = EE;
}

__global__ void k_dinv(const int* __restrict__ cnt, float* __restrict__ dinv) {
  int i = blockIdx.x * 256 + threadIdx.x;
  if (i < NN) dinv[i] = rsqrtf((float)cnt[i] + 1.0f);
}

__global__ void k_fill(const int* __restrict__ src, const int* __restrict__ dst,
                       int* __restrict__ cursor, int* __restrict__ col) {
  int e = blockIdx.x * 256 + threadIdx.x;
  if (e < EE) {
    int d = dst[e];
    int pos = atomicAdd(&cursor[d], 1);
    col[pos] = src[e];
  }
}

// hs[r][c] = dinv[r] * sum_k h[r][k] * W[k][c]
__global__ __launch_bounds__(256, 2)
void k_gemm(const float* __restrict__ h, const float* __restrict__ Wl,
            const float* __restrict__ dinv, float* __restrict__ hs) {
  __shared__ float Wlds[DD * DD];      // 64 KB
  for (int i = threadIdx.x; i < DD * DD; i += 256) Wlds[i] = Wl[i];
  __syncthreads();
  const int lane = threadIdx.x & 31;
  const int g = threadIdx.x >> 5;      // 0..7
  const int c4 = lane * 4;
  const int rbase = blockIdx.x * 64 + g * 8;
  if (rbase >= NN) return;
  float4 acc[8];
#pragma unroll
  for (int i = 0; i < 8; ++i) acc[i] = make_float4(0.f, 0.f, 0.f, 0.f);
  const bool full = (rbase + 8 <= NN);
  for (int k = 0; k < DD; k += 4) {
    float4 hv[8];
    if (full) {
#pragma unroll
      for (int i = 0; i < 8; ++i)
        hv[i] = *(const float4*)&h[(size_t)(rbase + i) * DD + k];
    } else {
#pragma unroll
      for (int i = 0; i < 8; ++i)
        hv[i] = (rbase + i < NN)
                    ? *(const float4*)&h[(size_t)(rbase + i) * DD + k]
                    : make_float4(0.f, 0.f, 0.f, 0.f);
    }
    const float4 w0 = *(const float4*)&Wlds[(k + 0) * DD + c4];
    const float4 w1 = *(const float4*)&Wlds[(k + 1) * DD + c4];
    const float4 w2 = *(const float4*)&Wlds[(k + 2) * DD + c4];
    const float4 w3 = *(const float4*)&Wlds[(k + 3) * DD + c4];
#pragma unroll
    for (int i = 0; i < 8; ++i) {
      acc[i].x = fmaf(hv[i].x, w0.x, acc[i].x);
      acc[i].x = fmaf(hv[i].y, w1.x, acc[i].x);
      acc[i].x = fmaf(hv[i].z, w2.x, acc[i].x);
      acc[i].x = fmaf(hv[i].w, w3.x, acc[i].x);
      acc[i].y = fmaf(hv[i].x, w0.y, acc[i].y);
      acc[i].y = fmaf(hv[i].y, w1.y, acc[i].y);
      acc[i].y = fmaf(hv[i].z, w2.y, acc[i].y);
      acc[i].y = fmaf(hv[i].w, w3.y, acc[i].y);
      acc[i].z = fmaf(hv[i].x, w0.z, acc[i].z);
      acc[i].z = fmaf(hv[i].y, w1.z, acc[i].z);
      acc[i].z = fmaf(hv[i].z, w2.z, acc[i].z);
      acc[i].z = fmaf(hv[i].w, w3.z, acc[i].z);
      acc[i].w = fmaf(hv[i].x, w0.w, acc[i].w);
      acc[i].w = fmaf(hv[i].y, w1.w, acc[i].w);
      acc[i].w = fmaf(hv[i].z, w2.w, acc[i].w);
      acc[i].w = fmaf(hv[i].w, w3.w, acc[i].w);
    }
  }
#pragma unroll
  for (int i = 0; i < 8; ++i) {
    int r = rbase + i;
    if (r < NN) {
      float dv = dinv[r];
      float4 o = acc[i];
      o.x *= dv; o.y *= dv; o.z *= dv; o.w *= dv;
      *(float4*)&hs[(size_t)r * DD + c4] = o;
    }
  }
}

// mode 0: hout = relu(dinv*(sum+self)+b); atomic-accumulate BN stats into stat[256]
// mode 1: out += relu(...)
__global__ __launch_bounds__(256)
void k_spmm(const float* __restrict__ hs, const int* __restrict__ rowptr,
            const int* __restrict__ col, const float* __restrict__ dinv,
            const float* __restrict__ bias, float* __restrict__ hout,
            float* __restrict__ out, float* __restrict__ stat,
            const int mode) {
  const int lane = threadIdx.x & 31;
  const int g = threadIdx.x >> 5;
  const int c4 = lane * 4;
  const float4 bv = *(const float4*)&bias[c4];
  float4 bsum = make_float4(0.f, 0.f, 0.f, 0.f);
  float4 bsq = make_float4(0.f, 0.f, 0.f, 0.f);
  for (int d0 = blockIdx.x * 8; d0 < NN; d0 += gridDim.x * 8) {
    const int d = d0 + g;
    if (d < NN) {
      const int rp1 = rowptr[d + 1];
      float4 acc = *(const float4*)&hs[(size_t)d * DD + c4];  // self-loop term
      for (int j = rowptr[d]; j < rp1; ++j) {
        const int s = col[j];
        const float4 v = *(const float4*)&hs[(size_t)s * DD + c4];
        acc.x += v.x; acc.y += v.y; acc.z += v.z; acc.w += v.w;
      }
      const float dv = dinv[d];
      float4 o;
      o.x = fmaxf(fmaf(acc.x, dv, bv.x), 0.f);
      o.y = fmaxf(fmaf(acc.y, dv, bv.y), 0.f);
      o.z = fmaxf(fmaf(acc.z, dv, bv.z), 0.f);
      o.w = fmaxf(fmaf(acc.w, dv, bv.w), 0.f);
      if (mode == 0) {
        *(float4*)&hout[(size_t)d * DD + c4] = o;
        bsum.x += o.x; bsum.y += o.y; bsum.z += o.z; bsum.w += o.w;
        bsq.x += o.x * o.x; bsq.y += o.y * o.y;
        bsq.z += o.z * o.z; bsq.w += o.w * o.w;
      } else {
        float4 po = *(const float4*)&out[(size_t)d * DD + c4];
        po.x += o.x; po.y += o.y; po.z += o.z; po.w += o.w;
        *(float4*)&out[(size_t)d * DD + c4] = po;
      }
    }
  }
  if (mode == 0) {
    __shared__ float red[256 * 8];
    float* my = &red[threadIdx.x * 8];
    my[0] = bsum.x; my[1] = bsum.y; my[2] = bsum.z; my[3] = bsum.w;
    my[4] = bsq.x;  my[5] = bsq.y;  my[6] = bsq.z;  my[7] = bsq.w;
    __syncthreads();
    const int t = threadIdx.x;          // slot t = lane*8 + q
    float s = 0.f;
#pragma unroll
    for (int gg = 0; gg < 8; ++gg) s += red[gg * 256 + t];
    atomicAdd(&stat[t], s);
  }
}

// finalize: stat[256] -> per-channel scale/shift
__global__ __launch_bounds__(256)
void k_bnfin(const float* __restrict__ stat, float* __restrict__ ss,
             const float* __restrict__ gamma, const float* __restrict__ beta) {
  __shared__ float tot[256];            // [kind*128 + c]
  const int t = threadIdx.x;
  const float s = stat[t];
  const int l = t >> 3, q = t & 7;
  const int c = l * 4 + (q & 3), kind = q >> 2;
  tot[kind * 128 + c] = s;
  __syncthreads();
  if (t < 128) {
    const float m = tot[t] * (1.0f / NN);
    const float var = tot[128 + t] * (1.0f / NN) - m * m;
    const float rs = rsqrtf(var + BN_EPS);
    const float sc = rs * gamma[t];
    ss[t] = sc;
    ss[128 + t] = beta[t] - m * sc;
  }
}

// h = h*scale + shift (in place); out += h
__global__ __launch_bounds__(256)
void k_bn(float* __restrict__ h, float* __restrict__ out,
          const float* __restrict__ ss) {
  const int i4 = blockIdx.x * 256 + threadIdx.x;   // exactly N*D/4 threads
  const int c4 = (i4 & 31) * 4;
  const float4 sc = *(const float4*)&ss[c4];
  const float4 sh = *(const float4*)&ss[128 + c4];
  float4 hv = ((const float4*)h)[i4];
  float4 o;
  o.x = fmaf(hv.x, sc.x, sh.x);
  o.y = fmaf(hv.y, sc.y, sh.y);
  o.z = fmaf(hv.z, sc.z, sh.z);
  o.w = fmaf(hv.w, sc.w, sh.w);
  ((float4*)h)[i4] = o;
  float4 po = ((float4*)out)[i4];
  po.x += o.x; po.y += o.y; po.z += o.z; po.w += o.w;
  ((float4*)out)[i4] = po;
}

extern "C" void kernel_launch(void* const* d_in, const int* in_sizes, int n_in,
                              void* d_out, int out_size, void* d_ws, size_t ws_size,
                              hipStream_t stream) {
  const float* x = (const float*)d_in[0];
  const int* ei = (const int*)d_in[1];
  const float* W = (const float*)d_in[2];
  const float* b = (const float*)d_in[3];
  const float* gamma = (const float*)d_in[4];
  const float* beta = (const float*)d_in[5];
  float* out = (float*)d_out;
  const int* srcv = ei;
  const int* dstv = ei + EE;

  char* w = (char*)d_ws;
  int* cnt = (int*)w;        w += (size_t)NPAD * 4;
  int* rowptr = (int*)w;     w += (size_t)NPAD * 4;
  int* cursor = (int*)w;     w += (size_t)NPAD * 4;
  int* lpre = (int*)w;       w += (size_t)NPAD * 4;
  int* bsum = (int*)w;       w += 512 * 4;
  int* bbase = (int*)w;      w += 512 * 4;
  int* col = (int*)w;        w += (size_t)EE * 4;
  float* dinv = (float*)w;   w += (size_t)NPAD * 4;
  float* ss = (float*)w;     w += 256 * 4;
  float* stat = (float*)w;   w += 512 * 4;        // 2 layers x 256 slots
  float* bufA = (float*)w;   w += (size_t)NN * DD * 4;
  float* bufB = (float*)w;   /* end */

  hipMemsetAsync(cnt, 0, NN * sizeof(int), stream);
  hipMemsetAsync(stat, 0, 512 * sizeof(float), stream);
  hipMemcpyAsync(out, x, (size_t)NN * DD * sizeof(float),
                 hipMemcpyDeviceToDevice, stream);

  k_count<<<(EE + 255) / 256, 256, 0, stream>>>(dstv, cnt);
  k_scanA<<<SCAN_BLOCKS, 256, 0, stream>>>(cnt, lpre, bsum);
  k_scanB<<<1, 512, 0, stream>>>(bsum, bbase);
  k_scanC<<<SCAN_BLOCKS, 256, 0, stream>>>(lpre, bbase, rowptr, cursor);
  k_dinv<<<(NN + 255) / 256, 256, 0, stream>>>(cnt, dinv);
  k_fill<<<(EE + 255) / 256, 256, 0, stream>>>(srcv, dstv, cursor, col);

  const float* hcur = x;
  for (int l = 0; l < 3; ++l) {
    k_gemm<<<(NN + 63) / 64, 256, 0, stream>>>(hcur, W + (size_t)l * DD * DD,
                                               dinv, bufB);
    if (l < 2) {
      k_spmm<<<SPMM_BLOCKS, 256, 0, stream>>>(bufB, rowptr, col, dinv,
                                              b + l * DD, bufA, nullptr,
                                              stat + l * 256, 0);
      k_bnfin<<<1, 256, 0, stream>>>(stat + l * 256, ss, gamma + l * DD,
                                     beta + l * DD);
      k_bn<<<(NN * DD / 4) / 256, 256, 0, stream>>>(bufA, out, ss);
      hcur = bufA;
    } else {
      k_spmm<<<SPMM_BLOCKS, 256, 0, stream>>>(bufB, rowptr, col, dinv,
                                              b + l * DD, nullptr, out,
                                              nullptr, 1);
    }
  }
}

// Round 4
// 1029.505 us; speedup vs baseline: 1.7544x; 1.0965x over previous
//
#include <hip/hip_runtime.h>
#include <hip/hip_bf16.h>

// GCN (3-layer, JK=sum) on MI355X.
// R4: hs stored as bf16 (halves gather bytes in k_spmm, which was
//     FETCH=400MB, 182us, BW-bound); fp32 accumulate; 2-deep gather unroll.

constexpr int NN = 100000;
constexpr int EE = 1600000;
constexpr int DD = 128;
constexpr float BN_EPS = 1e-5f;
constexpr int NPAD = 100096;
constexpr int SPMM_BLOCKS = 1024;
constexpr int SCAN_BLOCKS = (NN + 255) / 256;   // 391

__device__ __forceinline__ float bf2f(unsigned short u) {
  union { unsigned int i; float f; } v;
  v.i = ((unsigned int)u) << 16;
  return v.f;
}
__device__ __forceinline__ unsigned short f2bf(float f) {
  union { float f; unsigned int i; } v;
  v.f = f;
  unsigned int r = v.i + 0x7FFFu + ((v.i >> 16) & 1u);   // RNE
  return (unsigned short)(r >> 16);
}

__global__ void k_count(const int* __restrict__ dst, int* __restrict__ cnt) {
  int e = blockIdx.x * 256 + threadIdx.x;
  if (e < EE) atomicAdd(&cnt[dst[e]], 1);
}

__global__ __launch_bounds__(256)
void k_scanA(const int* __restrict__ cnt, int* __restrict__ lpre,
             int* __restrict__ bsum) {
  __shared__ int s[256];
  const int t = threadIdx.x;
  const int i = blockIdx.x * 256 + t;
  const int v = (i < NN) ? cnt[i] : 0;
  s[t] = v;
  __syncthreads();
  for (int off = 1; off < 256; off <<= 1) {
    int x = (t >= off) ? s[t - off] : 0;
    __syncthreads();
    s[t] += x;
    __syncthreads();
  }
  if (i < NN) lpre[i] = s[t] - v;             // exclusive
  if (t == 255) bsum[blockIdx.x] = s[255];
}

__global__ __launch_bounds__(512)
void k_scanB(const int* __restrict__ bsum, int* __restrict__ bbase) {
  __shared__ int s[512];
  const int t = threadIdx.x;
  const int v = (t < SCAN_BLOCKS) ? bsum[t] : 0;
  s[t] = v;
  __syncthreads();
  for (int off = 1; off < 512; off <<= 1) {
    int x = (t >= off) ? s[t - off] : 0;
    __syncthreads();
    s[t] += x;
    __syncthreads();
  }
  if (t < SCAN_BLOCKS) bbase[t] = s[t] - v;   // exclusive
}

__global__ __launch_bounds__(256)
void k_scanC(const int* __restrict__ lpre, const int* __restrict__ bbase,
             int* __restrict__ rowptr, int* __restrict__ cursor) {
  const int i = blockIdx.x * 256 + threadIdx.x;
  if (i < NN) {
    const int r = bbase[blockIdx.x] + lpre[i];
    rowptr[i] = r;
    cursor[i] = r;
  }
  if (i == 0) rowptr[NN] = EE;
}

__global__ void k_dinv(const int* __restrict__ cnt, float* __restrict__ dinv) {
  int i = blockIdx.x * 256 + threadIdx.x;
  if (i < NN) dinv[i] = rsqrtf((float)cnt[i] + 1.0f);
}

__global__ void k_fill(const int* __restrict__ src, const int* __restrict__ dst,
                       int* __restrict__ cursor, int* __restrict__ col) {
  int e = blockIdx.x * 256 + threadIdx.x;
  if (e < EE) {
    int d = dst[e];
    int pos = atomicAdd(&cursor[d], 1);
    col[pos] = src[e];
  }
}

// hs[r][c] = bf16( dinv[r] * sum_k h[r][k] * W[k][c] )
__global__ __launch_bounds__(256, 2)
void k_gemm(const float* __restrict__ h, const float* __restrict__ Wl,
            const float* __restrict__ dinv, unsigned short* __restrict__ hsb) {
  __shared__ float Wlds[DD * DD];      // 64 KB
  for (int i = threadIdx.x; i < DD * DD; i += 256) Wlds[i] = Wl[i];
  __syncthreads();
  const int lane = threadIdx.x & 31;
  const int g = threadIdx.x >> 5;      // 0..7
  const int c4 = lane * 4;
  const int rbase = blockIdx.x * 64 + g * 8;
  if (rbase >= NN) return;
  float4 acc[8];
#pragma unroll
  for (int i = 0; i < 8; ++i) acc[i] = make_float4(0.f, 0.f, 0.f, 0.f);
  const bool full = (rbase + 8 <= NN);
  for (int k = 0; k < DD; k += 4) {
    float4 hv[8];
    if (full) {
#pragma unroll
      for (int i = 0; i < 8; ++i)
        hv[i] = *(const float4*)&h[(size_t)(rbase + i) * DD + k];
    } else {
#pragma unroll
      for (int i = 0; i < 8; ++i)
        hv[i] = (rbase + i < NN)
                    ? *(const float4*)&h[(size_t)(rbase + i) * DD + k]
                    : make_float4(0.f, 0.f, 0.f, 0.f);
    }
    const float4 w0 = *(const float4*)&Wlds[(k + 0) * DD + c4];
    const float4 w1 = *(const float4*)&Wlds[(k + 1) * DD + c4];
    const float4 w2 = *(const float4*)&Wlds[(k + 2) * DD + c4];
    const float4 w3 = *(const float4*)&Wlds[(k + 3) * DD + c4];
#pragma unroll
    for (int i = 0; i < 8; ++i) {
      acc[i].x = fmaf(hv[i].x, w0.x, acc[i].x);
      acc[i].x = fmaf(hv[i].y, w1.x, acc[i].x);
      acc[i].x = fmaf(hv[i].z, w2.x, acc[i].x);
      acc[i].x = fmaf(hv[i].w, w3.x, acc[i].x);
      acc[i].y = fmaf(hv[i].x, w0.y, acc[i].y);
      acc[i].y = fmaf(hv[i].y, w1.y, acc[i].y);
      acc[i].y = fmaf(hv[i].z, w2.y, acc[i].y);
      acc[i].y = fmaf(hv[i].w, w3.y, acc[i].y);
      acc[i].z = fmaf(hv[i].x, w0.z, acc[i].z);
      acc[i].z = fmaf(hv[i].y, w1.z, acc[i].z);
      acc[i].z = fmaf(hv[i].z, w2.z, acc[i].z);
      acc[i].z = fmaf(hv[i].w, w3.z, acc[i].z);
      acc[i].w = fmaf(hv[i].x, w0.w, acc[i].w);
      acc[i].w = fmaf(hv[i].y, w1.w, acc[i].w);
      acc[i].w = fmaf(hv[i].z, w2.w, acc[i].w);
      acc[i].w = fmaf(hv[i].w, w3.w, acc[i].w);
    }
  }
#pragma unroll
  for (int i = 0; i < 8; ++i) {
    int r = rbase + i;
    if (r < NN) {
      float dv = dinv[r];
      ushort4 o4;
      o4.x = f2bf(acc[i].x * dv);
      o4.y = f2bf(acc[i].y * dv);
      o4.z = f2bf(acc[i].z * dv);
      o4.w = f2bf(acc[i].w * dv);
      *(ushort4*)&hsb[(size_t)r * DD + c4] = o4;
    }
  }
}

// mode 0: hout = relu(dinv*(sum+self)+b); atomic-accumulate BN stats into stat[256]
// mode 1: out += relu(...)
__global__ __launch_bounds__(256)
void k_spmm(const unsigned short* __restrict__ hsb, const int* __restrict__ rowptr,
            const int* __restrict__ col, const float* __restrict__ dinv,
            const float* __restrict__ bias, float* __restrict__ hout,
            float* __restrict__ out, float* __restrict__ stat,
            const int mode) {
  const int lane = threadIdx.x & 31;
  const int g = threadIdx.x >> 5;
  const int c4 = lane * 4;
  const float4 bv = *(const float4*)&bias[c4];
  float4 bsum = make_float4(0.f, 0.f, 0.f, 0.f);
  float4 bsq = make_float4(0.f, 0.f, 0.f, 0.f);
  for (int d0 = blockIdx.x * 8; d0 < NN; d0 += gridDim.x * 8) {
    const int d = d0 + g;
    if (d < NN) {
      const int e1 = rowptr[d + 1];
      ushort4 sv = *(const ushort4*)&hsb[(size_t)d * DD + c4];  // self-loop
      float4 acc;
      acc.x = bf2f(sv.x); acc.y = bf2f(sv.y);
      acc.z = bf2f(sv.z); acc.w = bf2f(sv.w);
      int j = rowptr[d];
      for (; j + 1 < e1; j += 2) {
        const int s0 = col[j];
        const int s1 = col[j + 1];
        const ushort4 v0 = *(const ushort4*)&hsb[(size_t)s0 * DD + c4];
        const ushort4 v1 = *(const ushort4*)&hsb[(size_t)s1 * DD + c4];
        acc.x += bf2f(v0.x) + bf2f(v1.x);
        acc.y += bf2f(v0.y) + bf2f(v1.y);
        acc.z += bf2f(v0.z) + bf2f(v1.z);
        acc.w += bf2f(v0.w) + bf2f(v1.w);
      }
      if (j < e1) {
        const int s0 = col[j];
        const ushort4 v0 = *(const ushort4*)&hsb[(size_t)s0 * DD + c4];
        acc.x += bf2f(v0.x); acc.y += bf2f(v0.y);
        acc.z += bf2f(v0.z); acc.w += bf2f(v0.w);
      }
      const float dv = dinv[d];
      float4 o;
      o.x = fmaxf(fmaf(acc.x, dv, bv.x), 0.f);
      o.y = fmaxf(fmaf(acc.y, dv, bv.y), 0.f);
      o.z = fmaxf(fmaf(acc.z, dv, bv.z), 0.f);
      o.w = fmaxf(fmaf(acc.w, dv, bv.w), 0.f);
      if (mode == 0) {
        *(float4*)&hout[(size_t)d * DD + c4] = o;
        bsum.x += o.x; bsum.y += o.y; bsum.z += o.z; bsum.w += o.w;
        bsq.x += o.x * o.x; bsq.y += o.y * o.y;
        bsq.z += o.z * o.z; bsq.w += o.w * o.w;
      } else {
        float4 po = *(const float4*)&out[(size_t)d * DD + c4];
        po.x += o.x; po.y += o.y; po.z += o.z; po.w += o.w;
        *(float4*)&out[(size_t)d * DD + c4] = po;
      }
    }
  }
  if (mode == 0) {
    __shared__ float red[256 * 8];
    float* my = &red[threadIdx.x * 8];
    my[0] = bsum.x; my[1] = bsum.y; my[2] = bsum.z; my[3] = bsum.w;
    my[4] = bsq.x;  my[5] = bsq.y;  my[6] = bsq.z;  my[7] = bsq.w;
    __syncthreads();
    const int t = threadIdx.x;          // slot t = lane*8 + q
    float s = 0.f;
#pragma unroll
    for (int gg = 0; gg < 8; ++gg) s += red[gg * 256 + t];
    atomicAdd(&stat[t], s);
  }
}

// finalize: stat[256] -> per-channel scale/shift
__global__ __launch_bounds__(256)
void k_bnfin(const float* __restrict__ stat, float* __restrict__ ss,
             const float* __restrict__ gamma, const float* __restrict__ beta) {
  __shared__ float tot[256];            // [kind*128 + c]
  const int t = threadIdx.x;
  const float s = stat[t];
  const int l = t >> 3, q = t & 7;
  const int c = l * 4 + (q & 3), kind = q >> 2;
  tot[kind * 128 + c] = s;
  __syncthreads();
  if (t < 128) {
    const float m = tot[t] * (1.0f / NN);
    const float var = tot[128 + t] * (1.0f / NN) - m * m;
    const float rs = rsqrtf(var + BN_EPS);
    const float sc = rs * gamma[t];
    ss[t] = sc;
    ss[128 + t] = beta[t] - m * sc;
  }
}

// h = h*scale + shift (in place); out += h
__global__ __launch_bounds__(256)
void k_bn(float* __restrict__ h, float* __restrict__ out,
          const float* __restrict__ ss) {
  const int i4 = blockIdx.x * 256 + threadIdx.x;   // exactly N*D/4 threads
  const int c4 = (i4 & 31) * 4;
  const float4 sc = *(const float4*)&ss[c4];
  const float4 sh = *(const float4*)&ss[128 + c4];
  float4 hv = ((const float4*)h)[i4];
  float4 o;
  o.x = fmaf(hv.x, sc.x, sh.x);
  o.y = fmaf(hv.y, sc.y, sh.y);
  o.z = fmaf(hv.z, sc.z, sh.z);
  o.w = fmaf(hv.w, sc.w, sh.w);
  ((float4*)h)[i4] = o;
  float4 po = ((float4*)out)[i4];
  po.x += o.x; po.y += o.y; po.z += o.z; po.w += o.w;
  ((float4*)out)[i4] = po;
}

extern "C" void kernel_launch(void* const* d_in, const int* in_sizes, int n_in,
                              void* d_out, int out_size, void* d_ws, size_t ws_size,
                              hipStream_t stream) {
  const float* x = (const float*)d_in[0];
  const int* ei = (const int*)d_in[1];
  const float* W = (const float*)d_in[2];
  const float* b = (const float*)d_in[3];
  const float* gamma = (const float*)d_in[4];
  const float* beta = (const float*)d_in[5];
  float* out = (float*)d_out;
  const int* srcv = ei;
  const int* dstv = ei + EE;

  char* w = (char*)d_ws;
  int* cnt = (int*)w;        w += (size_t)NPAD * 4;
  int* rowptr = (int*)w;     w += (size_t)NPAD * 4;
  int* cursor = (int*)w;     w += (size_t)NPAD * 4;
  int* lpre = (int*)w;       w += (size_t)NPAD * 4;
  int* bsum = (int*)w;       w += 512 * 4;
  int* bbase = (int*)w;      w += 512 * 4;
  int* col = (int*)w;        w += (size_t)EE * 4;
  float* dinv = (float*)w;   w += (size_t)NPAD * 4;
  float* ss = (float*)w;     w += 256 * 4;
  float* stat = (float*)w;   w += 512 * 4;        // 2 layers x 256 slots
  float* bufA = (float*)w;   w += (size_t)NN * DD * 4;      // h (fp32)
  unsigned short* hsb = (unsigned short*)w;       // hs (bf16)

  hipMemsetAsync(cnt, 0, NN * sizeof(int), stream);
  hipMemsetAsync(stat, 0, 512 * sizeof(float), stream);
  hipMemcpyAsync(out, x, (size_t)NN * DD * sizeof(float),
                 hipMemcpyDeviceToDevice, stream);

  k_count<<<(EE + 255) / 256, 256, 0, stream>>>(dstv, cnt);
  k_scanA<<<SCAN_BLOCKS, 256, 0, stream>>>(cnt, lpre, bsum);
  k_scanB<<<1, 512, 0, stream>>>(bsum, bbase);
  k_scanC<<<SCAN_BLOCKS, 256, 0, stream>>>(lpre, bbase, rowptr, cursor);
  k_dinv<<<(NN + 255) / 256, 256, 0, stream>>>(cnt, dinv);
  k_fill<<<(EE + 255) / 256, 256, 0, stream>>>(srcv, dstv, cursor, col);

  const float* hcur = x;
  for (int l = 0; l < 3; ++l) {
    k_gemm<<<(NN + 63) / 64, 256, 0, stream>>>(hcur, W + (size_t)l * DD * DD,
                                               dinv, hsb);
    if (l < 2) {
      k_spmm<<<SPMM_BLOCKS, 256, 0, stream>>>(hsb, rowptr, col, dinv,
                                              b + l * DD, bufA, nullptr,
                                              stat + l * 256, 0);
      k_bnfin<<<1, 256, 0, stream>>>(stat + l * 256, ss, gamma + l * DD,
                                     beta + l * DD);
      k_bn<<<(NN * DD / 4) / 256, 256, 0, stream>>>(bufA, out, ss);
      hcur = bufA;
    } else {
      k_spmm<<<SPMM_BLOCKS, 256, 0, stream>>>(hsb, rowptr, col, dinv,
                                              b + l * DD, nullptr, out,
                                              nullptr, 1);
    }
  }
}

// Round 5
// 848.155 us; speedup vs baseline: 2.1295x; 1.2138x over previous
//
#include <hip/hip_runtime.h>
#include <hip/hip_bf16.h>

// GCN (3-layer, JK=sum) on MI355X.
// R5: spmm MLP overhaul — grid 6250 (full occupancy; was 1024 blocks = 39%),
//     16 lanes/row x 16B loads, 4-deep gather unroll (16 loads in flight/wave),
//     BN stats via per-block partials + parallel reduce (no atomics).

constexpr int NN = 100000;
constexpr int EE = 1600000;
constexpr int DD = 128;
constexpr float BN_EPS = 1e-5f;
constexpr int NPAD = 100096;
constexpr int SCAN_BLOCKS = (NN + 255) / 256;   // 391
constexpr int SPMM_GRID = NN / 16;              // 6250 (exact: 6250*16=100000)

__device__ __forceinline__ float bfhi(unsigned int u) {
  union { unsigned int i; float f; } v; v.i = u & 0xffff0000u; return v.f;
}
__device__ __forceinline__ float bflo(unsigned int u) {
  union { unsigned int i; float f; } v; v.i = u << 16; return v.f;
}
__device__ __forceinline__ unsigned short f2bf(float f) {
  union { float f; unsigned int i; } v;
  v.f = f;
  unsigned int r = v.i + 0x7FFFu + ((v.i >> 16) & 1u);   // RNE
  return (unsigned short)(r >> 16);
}
__device__ __forceinline__ void acc8(uint4 u, float4& a0, float4& a1) {
  a0.x += bflo(u.x); a0.y += bfhi(u.x);
  a0.z += bflo(u.y); a0.w += bfhi(u.y);
  a1.x += bflo(u.z); a1.y += bfhi(u.z);
  a1.z += bflo(u.w); a1.w += bfhi(u.w);
}

__global__ void k_count(const int* __restrict__ dst, int* __restrict__ cnt) {
  int e = blockIdx.x * 256 + threadIdx.x;
  if (e < EE) atomicAdd(&cnt[dst[e]], 1);
}

__global__ __launch_bounds__(256)
void k_scanA(const int* __restrict__ cnt, int* __restrict__ lpre,
             int* __restrict__ bsum) {
  __shared__ int s[256];
  const int t = threadIdx.x;
  const int i = blockIdx.x * 256 + t;
  const int v = (i < NN) ? cnt[i] : 0;
  s[t] = v;
  __syncthreads();
  for (int off = 1; off < 256; off <<= 1) {
    int x = (t >= off) ? s[t - off] : 0;
    __syncthreads();
    s[t] += x;
    __syncthreads();
  }
  if (i < NN) lpre[i] = s[t] - v;             // exclusive
  if (t == 255) bsum[blockIdx.x] = s[255];
}

__global__ __launch_bounds__(512)
void k_scanB(const int* __restrict__ bsum, int* __restrict__ bbase) {
  __shared__ int s[512];
  const int t = threadIdx.x;
  const int v = (t < SCAN_BLOCKS) ? bsum[t] : 0;
  s[t] = v;
  __syncthreads();
  for (int off = 1; off < 512; off <<= 1) {
    int x = (t >= off) ? s[t - off] : 0;
    __syncthreads();
    s[t] += x;
    __syncthreads();
  }
  if (t < SCAN_BLOCKS) bbase[t] = s[t] - v;   // exclusive
}

__global__ __launch_bounds__(256)
void k_scanC(const int* __restrict__ lpre, const int* __restrict__ bbase,
             int* __restrict__ rowptr, int* __restrict__ cursor) {
  const int i = blockIdx.x * 256 + threadIdx.x;
  if (i < NN) {
    const int r = bbase[blockIdx.x] + lpre[i];
    rowptr[i] = r;
    cursor[i] = r;
  }
  if (i == 0) rowptr[NN] = EE;
}

__global__ void k_dinv(const int* __restrict__ cnt, float* __restrict__ dinv) {
  int i = blockIdx.x * 256 + threadIdx.x;
  if (i < NN) dinv[i] = rsqrtf((float)cnt[i] + 1.0f);
}

__global__ void k_fill(const int* __restrict__ src, const int* __restrict__ dst,
                       int* __restrict__ cursor, int* __restrict__ col) {
  int e = blockIdx.x * 256 + threadIdx.x;
  if (e < EE) {
    int d = dst[e];
    int pos = atomicAdd(&cursor[d], 1);
    col[pos] = src[e];
  }
}

// hs[r][c] = bf16( dinv[r] * sum_k h[r][k] * W[k][c] )
__global__ __launch_bounds__(256, 2)
void k_gemm(const float* __restrict__ h, const float* __restrict__ Wl,
            const float* __restrict__ dinv, unsigned short* __restrict__ hsb) {
  __shared__ float Wlds[DD * DD];      // 64 KB
  for (int i = threadIdx.x; i < DD * DD; i += 256) Wlds[i] = Wl[i];
  __syncthreads();
  const int lane = threadIdx.x & 31;
  const int g = threadIdx.x >> 5;      // 0..7
  const int c4 = lane * 4;
  const int rbase = blockIdx.x * 64 + g * 8;
  if (rbase >= NN) return;
  float4 acc[8];
#pragma unroll
  for (int i = 0; i < 8; ++i) acc[i] = make_float4(0.f, 0.f, 0.f, 0.f);
  const bool full = (rbase + 8 <= NN);
  for (int k = 0; k < DD; k += 4) {
    float4 hv[8];
    if (full) {
#pragma unroll
      for (int i = 0; i < 8; ++i)
        hv[i] = *(const float4*)&h[(size_t)(rbase + i) * DD + k];
    } else {
#pragma unroll
      for (int i = 0; i < 8; ++i)
        hv[i] = (rbase + i < NN)
                    ? *(const float4*)&h[(size_t)(rbase + i) * DD + k]
                    : make_float4(0.f, 0.f, 0.f, 0.f);
    }
    const float4 w0 = *(const float4*)&Wlds[(k + 0) * DD + c4];
    const float4 w1 = *(const float4*)&Wlds[(k + 1) * DD + c4];
    const float4 w2 = *(const float4*)&Wlds[(k + 2) * DD + c4];
    const float4 w3 = *(const float4*)&Wlds[(k + 3) * DD + c4];
#pragma unroll
    for (int i = 0; i < 8; ++i) {
      acc[i].x = fmaf(hv[i].x, w0.x, acc[i].x);
      acc[i].x = fmaf(hv[i].y, w1.x, acc[i].x);
      acc[i].x = fmaf(hv[i].z, w2.x, acc[i].x);
      acc[i].x = fmaf(hv[i].w, w3.x, acc[i].x);
      acc[i].y = fmaf(hv[i].x, w0.y, acc[i].y);
      acc[i].y = fmaf(hv[i].y, w1.y, acc[i].y);
      acc[i].y = fmaf(hv[i].z, w2.y, acc[i].y);
      acc[i].y = fmaf(hv[i].w, w3.y, acc[i].y);
      acc[i].z = fmaf(hv[i].x, w0.z, acc[i].z);
      acc[i].z = fmaf(hv[i].y, w1.z, acc[i].z);
      acc[i].z = fmaf(hv[i].z, w2.z, acc[i].z);
      acc[i].z = fmaf(hv[i].w, w3.z, acc[i].z);
      acc[i].w = fmaf(hv[i].x, w0.w, acc[i].w);
      acc[i].w = fmaf(hv[i].y, w1.w, acc[i].w);
      acc[i].w = fmaf(hv[i].z, w2.w, acc[i].w);
      acc[i].w = fmaf(hv[i].w, w3.w, acc[i].w);
    }
  }
#pragma unroll
  for (int i = 0; i < 8; ++i) {
    int r = rbase + i;
    if (r < NN) {
      float dv = dinv[r];
      ushort4 o4;
      o4.x = f2bf(acc[i].x * dv);
      o4.y = f2bf(acc[i].y * dv);
      o4.z = f2bf(acc[i].z * dv);
      o4.w = f2bf(acc[i].w * dv);
      *(ushort4*)&hsb[(size_t)r * DD + c4] = o4;
    }
  }
}

// 16 lanes per dst row, 16 rows per block, 4-deep gather unroll.
// mode 0: hout = relu(dinv*(sum+self)+b); per-block BN partials -> partials[slot][blk]
// mode 1: out += relu(...)
__global__ __launch_bounds__(256)
void k_spmm(const unsigned short* __restrict__ hsb, const int* __restrict__ rowptr,
            const int* __restrict__ col, const float* __restrict__ dinv,
            const float* __restrict__ bias, float* __restrict__ hout,
            float* __restrict__ out, float* __restrict__ partials,
            const int mode) {
  const int lane = threadIdx.x & 15;     // 16 lanes / row
  const int g = threadIdx.x >> 4;        // 0..15 rows / block
  const int c8 = lane * 8;
  const int d = blockIdx.x * 16 + g;
  float4 a0 = make_float4(0.f, 0.f, 0.f, 0.f);
  float4 a1 = make_float4(0.f, 0.f, 0.f, 0.f);
  float4 bs0 = a0, bs1 = a0, q0 = a0, q1 = a0;
  if (d < NN) {
    const unsigned short* rowp = &hsb[(size_t)d * DD + c8];
    acc8(*(const uint4*)rowp, a0, a1);                 // self-loop term
    int j = rowptr[d];
    const int e1 = rowptr[d + 1];
    for (; j + 3 < e1; j += 4) {
      const int s0 = col[j], s1 = col[j + 1], s2 = col[j + 2], s3 = col[j + 3];
      const uint4 u0 = *(const uint4*)&hsb[(size_t)s0 * DD + c8];
      const uint4 u1 = *(const uint4*)&hsb[(size_t)s1 * DD + c8];
      const uint4 u2 = *(const uint4*)&hsb[(size_t)s2 * DD + c8];
      const uint4 u3 = *(const uint4*)&hsb[(size_t)s3 * DD + c8];
      acc8(u0, a0, a1); acc8(u1, a0, a1);
      acc8(u2, a0, a1); acc8(u3, a0, a1);
    }
    for (; j < e1; ++j) {
      const uint4 u0 = *(const uint4*)&hsb[(size_t)col[j] * DD + c8];
      acc8(u0, a0, a1);
    }
    const float dv = dinv[d];
    const float4 b0 = *(const float4*)&bias[c8];
    const float4 b1 = *(const float4*)&bias[c8 + 4];
    float4 o0, o1;
    o0.x = fmaxf(fmaf(a0.x, dv, b0.x), 0.f);
    o0.y = fmaxf(fmaf(a0.y, dv, b0.y), 0.f);
    o0.z = fmaxf(fmaf(a0.z, dv, b0.z), 0.f);
    o0.w = fmaxf(fmaf(a0.w, dv, b0.w), 0.f);
    o1.x = fmaxf(fmaf(a1.x, dv, b1.x), 0.f);
    o1.y = fmaxf(fmaf(a1.y, dv, b1.y), 0.f);
    o1.z = fmaxf(fmaf(a1.z, dv, b1.z), 0.f);
    o1.w = fmaxf(fmaf(a1.w, dv, b1.w), 0.f);
    if (mode == 0) {
      *(float4*)&hout[(size_t)d * DD + c8] = o0;
      *(float4*)&hout[(size_t)d * DD + c8 + 4] = o1;
      bs0 = o0; bs1 = o1;
      q0.x = o0.x * o0.x; q0.y = o0.y * o0.y;
      q0.z = o0.z * o0.z; q0.w = o0.w * o0.w;
      q1.x = o1.x * o1.x; q1.y = o1.y * o1.y;
      q1.z = o1.z * o1.z; q1.w = o1.w * o1.w;
    } else {
      float4 p0 = *(const float4*)&out[(size_t)d * DD + c8];
      float4 p1 = *(const float4*)&out[(size_t)d * DD + c8 + 4];
      p0.x += o0.x; p0.y += o0.y; p0.z += o0.z; p0.w += o0.w;
      p1.x += o1.x; p1.y += o1.y; p1.z += o1.z; p1.w += o1.w;
      *(float4*)&out[(size_t)d * DD + c8] = p0;
      *(float4*)&out[(size_t)d * DD + c8 + 4] = p1;
    }
  }
  if (mode == 0) {
    // reduce 16 row-groups -> 256 slots; slot = lane*16 + q
    // q in [0,8): sum of channel lane*8+q ; q in [8,16): sumsq of channel lane*8+q-8
    __shared__ float red[256 * 16];
    float* my = &red[threadIdx.x * 16];
    my[0] = bs0.x; my[1] = bs0.y; my[2] = bs0.z; my[3] = bs0.w;
    my[4] = bs1.x; my[5] = bs1.y; my[6] = bs1.z; my[7] = bs1.w;
    my[8] = q0.x;  my[9] = q0.y;  my[10] = q0.z; my[11] = q0.w;
    my[12] = q1.x; my[13] = q1.y; my[14] = q1.z; my[15] = q1.w;
    __syncthreads();
    const int t = threadIdx.x;          // slot; contributors at tid = gg*16 + (t>>4), elem t&15
    float s = 0.f;
#pragma unroll
    for (int gg = 0; gg < 16; ++gg) s += red[gg * 256 + t];
    partials[(size_t)t * SPMM_GRID + blockIdx.x] = s;
  }
}

// one block per slot: stat[slot] = sum over blocks of partials[slot][*]
__global__ __launch_bounds__(256)
void k_bnred(const float* __restrict__ partials, float* __restrict__ stat) {
  __shared__ float s[256];
  const int slot = blockIdx.x;
  float v = 0.f;
  for (int i = threadIdx.x; i < SPMM_GRID; i += 256)
    v += partials[(size_t)slot * SPMM_GRID + i];
  s[threadIdx.x] = v;
  __syncthreads();
  for (int off = 128; off; off >>= 1) {
    if (threadIdx.x < off) s[threadIdx.x] += s[threadIdx.x + off];
    __syncthreads();
  }
  if (threadIdx.x == 0) stat[slot] = s[0];
}

// stat[256] -> per-channel scale/shift.  slot = lane16*16+q
__global__ __launch_bounds__(256)
void k_bnfin(const float* __restrict__ stat, float* __restrict__ ss,
             const float* __restrict__ gamma, const float* __restrict__ beta) {
  __shared__ float tot[256];            // [kind*128 + c]
  const int t = threadIdx.x;
  const float s = stat[t];
  const int lane16 = t >> 4, q = t & 15;
  const int c = lane16 * 8 + (q & 7), kind = q >> 3;
  tot[kind * 128 + c] = s;
  __syncthreads();
  if (t < 128) {
    const float m = tot[t] * (1.0f / NN);
    const float var = tot[128 + t] * (1.0f / NN) - m * m;
    const float rs = rsqrtf(var + BN_EPS);
    const float sc = rs * gamma[t];
    ss[t] = sc;
    ss[128 + t] = beta[t] - m * sc;
  }
}

// h = h*scale + shift (in place); out += h
__global__ __launch_bounds__(256)
void k_bn(float* __restrict__ h, float* __restrict__ out,
          const float* __restrict__ ss) {
  const int i4 = blockIdx.x * 256 + threadIdx.x;   // exactly N*D/4 threads
  const int c4 = (i4 & 31) * 4;
  const float4 sc = *(const float4*)&ss[c4];
  const float4 sh = *(const float4*)&ss[128 + c4];
  float4 hv = ((const float4*)h)[i4];
  float4 o;
  o.x = fmaf(hv.x, sc.x, sh.x);
  o.y = fmaf(hv.y, sc.y, sh.y);
  o.z = fmaf(hv.z, sc.z, sh.z);
  o.w = fmaf(hv.w, sc.w, sh.w);
  ((float4*)h)[i4] = o;
  float4 po = ((float4*)out)[i4];
  po.x += o.x; po.y += o.y; po.z += o.z; po.w += o.w;
  ((float4*)out)[i4] = po;
}

extern "C" void kernel_launch(void* const* d_in, const int* in_sizes, int n_in,
                              void* d_out, int out_size, void* d_ws, size_t ws_size,
                              hipStream_t stream) {
  const float* x = (const float*)d_in[0];
  const int* ei = (const int*)d_in[1];
  const float* W = (const float*)d_in[2];
  const float* b = (const float*)d_in[3];
  const float* gamma = (const float*)d_in[4];
  const float* beta = (const float*)d_in[5];
  float* out = (float*)d_out;
  const int* srcv = ei;
  const int* dstv = ei + EE;

  char* w = (char*)d_ws;
  int* cnt = (int*)w;        w += (size_t)NPAD * 4;
  int* rowptr = (int*)w;     w += (size_t)NPAD * 4;
  int* cursor = (int*)w;     w += (size_t)NPAD * 4;
  int* lpre = (int*)w;       w += (size_t)NPAD * 4;
  int* bsum = (int*)w;       w += 512 * 4;
  int* bbase = (int*)w;      w += 512 * 4;
  int* col = (int*)w;        w += (size_t)EE * 4;
  float* dinv = (float*)w;   w += (size_t)NPAD * 4;
  float* ss = (float*)w;     w += 256 * 4;
  float* stat = (float*)w;   w += 256 * 4;
  float* partials = (float*)w; w += (size_t)256 * SPMM_GRID * 4;   // 6.4 MB
  float* bufA = (float*)w;   w += (size_t)NN * DD * 4;             // h (fp32)
  unsigned short* hsb = (unsigned short*)w;                        // hs (bf16)

  hipMemsetAsync(cnt, 0, NN * sizeof(int), stream);
  hipMemcpyAsync(out, x, (size_t)NN * DD * sizeof(float),
                 hipMemcpyDeviceToDevice, stream);

  k_count<<<(EE + 255) / 256, 256, 0, stream>>>(dstv, cnt);
  k_scanA<<<SCAN_BLOCKS, 256, 0, stream>>>(cnt, lpre, bsum);
  k_scanB<<<1, 512, 0, stream>>>(bsum, bbase);
  k_scanC<<<SCAN_BLOCKS, 256, 0, stream>>>(lpre, bbase, rowptr, cursor);
  k_dinv<<<(NN + 255) / 256, 256, 0, stream>>>(cnt, dinv);
  k_fill<<<(EE + 255) / 256, 256, 0, stream>>>(srcv, dstv, cursor, col);

  const float* hcur = x;
  for (int l = 0; l < 3; ++l) {
    k_gemm<<<(NN + 63) / 64, 256, 0, stream>>>(hcur, W + (size_t)l * DD * DD,
                                               dinv, hsb);
    if (l < 2) {
      k_spmm<<<SPMM_GRID, 256, 0, stream>>>(hsb, rowptr, col, dinv,
                                            b + l * DD, bufA, nullptr,
                                            partials, 0);
      k_bnred<<<256, 256, 0, stream>>>(partials, stat);
      k_bnfin<<<1, 256, 0, stream>>>(stat, ss, gamma + l * DD, beta + l * DD);
      k_bn<<<(NN * DD / 4) / 256, 256, 0, stream>>>(bufA, out, ss);
      hcur = bufA;
    } else {
      k_spmm<<<SPMM_GRID, 256, 0, stream>>>(hsb, rowptr, col, dinv,
                                            b + l * DD, nullptr, out,
                                            nullptr, 1);
    }
  }
}